// Round 4
// baseline (111.348 us; speedup 1.0000x reference)
//
#include <hip/hip_runtime.h>
#include <math.h>

#define LSEQ 4096
#define TDIM 25
#define BDIM 257
#define RDIM 8
#define KDIM 3

#define S_CHUNK 4
#define W_WARM 16
#define TOT (S_CHUNK + W_WARM)     // 20 steps per thread
#define NCHUNK (LSEQ / S_CHUNK)    // 1024

__device__ __forceinline__ float rcp_f(float x) {
    return __builtin_amdgcn_rcpf(x);    // v_rcp_f32, ~1 ULP
}
__device__ __forceinline__ float elu_f(float x) {
    return x > 0.f ? x : (__expf(x) - 1.f);
}
__device__ __forceinline__ float sig_f(float x) {
    return rcp_f(1.f + __expf(-x));
}
__device__ __forceinline__ float tanh_f(float x) {
    float e = __expf(2.f * x);
    return 1.f - 2.f * rcp_f(e + 1.f);
}

// ---------------- Kernel 1: encoder (parallel over L x B) ----------------
__global__ __launch_bounds__(320) void k_enc(
    const float* __restrict__ x, const float* __restrict__ knobs,
    const float* __restrict__ W_enc, const float* __restrict__ b_enc,
    const float* __restrict__ W_enc2, const float* __restrict__ b_enc2,
    const float* __restrict__ W_enc3, const float* __restrict__ b_enc3,
    const float* __restrict__ Wk, const float* __restrict__ bk,
    float* __restrict__ z_enc, float* __restrict__ kn)
{
    const int l = blockIdx.x;
    const int b = threadIdx.x;
    if (b < BDIM) {
        const float* xl = x + (size_t)l * TDIM * BDIM + b;
        float xr[TDIM];
        #pragma unroll
        for (int t = 0; t < TDIM; ++t) xr[t] = xl[(size_t)t * BDIM];
        float z1[RDIM];
        #pragma unroll
        for (int r = 0; r < RDIM; ++r) {
            float a = b_enc[r];
            #pragma unroll
            for (int t = 0; t < TDIM; ++t) a = fmaf(W_enc[r * TDIM + t], xr[t], a);
            z1[r] = elu_f(a);
        }
        float z2[RDIM / 2];
        #pragma unroll
        for (int r = 0; r < RDIM / 2; ++r) {
            float a = b_enc2[r];
            #pragma unroll
            for (int j = 0; j < RDIM; ++j) a = fmaf(W_enc2[r * RDIM + j], z1[j], a);
            z2[r] = elu_f(a);
        }
        float z30 = b_enc3[0], z31 = b_enc3[1];
        #pragma unroll
        for (int j = 0; j < RDIM / 2; ++j) {
            z30 = fmaf(W_enc3[j], z2[j], z30);
            z31 = fmaf(W_enc3[RDIM / 2 + j], z2[j], z31);
        }
        reinterpret_cast<float2*>(z_enc)[(size_t)l * BDIM + b] =
            make_float2(elu_f(z30), elu_f(z31));
    } else if (b == BDIM) {
        float k0 = knobs[l * KDIM + 0], k1 = knobs[l * KDIM + 1], k2 = knobs[l * KDIM + 2];
        float2 kv;
        kv.x = bk[0] + Wk[0 * 5 + 2] * k0 + Wk[0 * 5 + 3] * k1 + Wk[0 * 5 + 4] * k2;
        kv.y = bk[1] + Wk[1 * 5 + 2] * k0 + Wk[1 * 5 + 3] * k1 + Wk[1 * 5 + 4] * k2;
        reinterpret_cast<float2*>(kn)[l] = kv;
    }
}

// ---------------- Kernel 2: chunked fused LSTM1 -> mid -> LSTM2 ----------------
__global__ __launch_bounds__(64) void k_lstm(
    const float* __restrict__ z_enc, const float* __restrict__ kn,
    const float* __restrict__ Wih1, const float* __restrict__ Whh1,
    const float* __restrict__ bih1, const float* __restrict__ bhh1,
    const float* __restrict__ Wk,
    const float* __restrict__ Wih2, const float* __restrict__ Whh2,
    const float* __restrict__ bih2, const float* __restrict__ bhh2,
    float* __restrict__ h2out)
{
    __shared__ float2 zs[TOT][64];
    __shared__ float2 ks[TOT];

    const int tid = threadIdx.x;
    const int b = blockIdx.x * 64 + tid;
    const int bb = b < BDIM ? b : BDIM - 1;     // clamp for safe reads
    const bool active = b < BDIM;
    const int chunk = blockIdx.y;
    const int l0 = chunk * S_CHUNK;
    const int ls = l0 - W_WARM;                 // may be negative (chunks 0..3)

    const float2* ze = reinterpret_cast<const float2*>(z_enc);
    const float2* knv = reinterpret_cast<const float2*>(kn);
    float2* ho = reinterpret_cast<float2*>(h2out);

    // ---- stage: TOT independent coalesced loads, one latency ----
    #pragma unroll
    for (int i = 0; i < TOT; ++i) {
        int l = ls + i; int lc = l < 0 ? 0 : l;
        zs[i][tid] = ze[(size_t)lc * BDIM + bb];
    }
    if (tid < TOT) {
        int l = ls + tid; int lc = l < 0 ? 0 : l;
        ks[tid] = knv[lc];
    }
    __syncthreads();

    // ---- weights (uniform -> SGPRs) ----
    float wi1[8][2], wh1[8][2], bb1[8];
    float wi2[8][2], wh2[8][2], bb2[8];
    #pragma unroll
    for (int j = 0; j < 8; ++j) {
        wi1[j][0] = Wih1[j * 2]; wi1[j][1] = Wih1[j * 2 + 1];
        wh1[j][0] = Whh1[j * 2]; wh1[j][1] = Whh1[j * 2 + 1];
        bb1[j] = bih1[j] + bhh1[j];
        wi2[j][0] = Wih2[j * 2]; wi2[j][1] = Wih2[j * 2 + 1];
        wh2[j][0] = Whh2[j * 2]; wh2[j][1] = Whh2[j * 2 + 1];
        bb2[j] = bih2[j] + bhh2[j];
    }
    const float wk00 = Wk[0], wk01 = Wk[1], wk10 = Wk[5], wk11 = Wk[6];

    float h1x = 0.f, h1y = 0.f, c1x = 0.f, c1y = 0.f;
    float h2x = 0.f, h2y = 0.f, c2x = 0.f, c2y = 0.f;

    #pragma unroll 4
    for (int i = 0; i < TOT; ++i) {
        const int l = ls + i;
        if (l < 0) continue;                    // wave-uniform: state stays zero
        float2 xe = zs[i][tid];
        float2 kv = ks[i];
        // ---- LSTM1 ---- gate order i,f,g,o (4H=8, H=2)
        float g[8];
        #pragma unroll
        for (int j = 0; j < 8; ++j)
            g[j] = fmaf(wh1[j][1], h1y, fmaf(wh1[j][0], h1x,
                   fmaf(wi1[j][1], xe.y, fmaf(wi1[j][0], xe.x, bb1[j]))));
        c1x = fmaf(sig_f(g[2]), c1x, sig_f(g[0]) * tanh_f(g[4]));
        c1y = fmaf(sig_f(g[3]), c1y, sig_f(g[1]) * tanh_f(g[5]));
        h1x = sig_f(g[6]) * tanh_f(c1x);
        h1y = sig_f(g[7]) * tanh_f(c1y);
        // ---- mid (knobs) layer ----
        float e0 = elu_f(h1x), e1 = elu_f(h1y);
        float m0 = elu_f(fmaf(wk01, e1, fmaf(wk00, e0, kv.x)));
        float m1 = elu_f(fmaf(wk11, e1, fmaf(wk10, e0, kv.y)));
        // ---- LSTM2 ----
        float g2[8];
        #pragma unroll
        for (int j = 0; j < 8; ++j)
            g2[j] = fmaf(wh2[j][1], h2y, fmaf(wh2[j][0], h2x,
                    fmaf(wi2[j][1], m1, fmaf(wi2[j][0], m0, bb2[j]))));
        c2x = fmaf(sig_f(g2[2]), c2x, sig_f(g2[0]) * tanh_f(g2[4]));
        c2y = fmaf(sig_f(g2[3]), c2y, sig_f(g2[1]) * tanh_f(g2[5]));
        h2x = sig_f(g2[6]) * tanh_f(c2x);
        h2y = sig_f(g2[7]) * tanh_f(c2y);
        if (active && l >= l0)
            ho[(size_t)l * BDIM + b] = make_float2(h2x, h2y);
    }
}

// ---------------- Kernel 3: decoder + residual (parallel over L x B) ----------------
__global__ __launch_bounds__(320) void k_dec(
    const float* __restrict__ h2, const float* __restrict__ x,
    const float* __restrict__ W_dec3, const float* __restrict__ b_dec3,
    const float* __restrict__ W_dec2, const float* __restrict__ b_dec2,
    const float* __restrict__ W_dec, const float* __restrict__ b_dec,
    float* __restrict__ out)
{
    const int l = blockIdx.x;
    const int b = threadIdx.x;
    if (b >= BDIM) return;
    float2 h = reinterpret_cast<const float2*>(h2)[(size_t)l * BDIM + b];
    float e0 = elu_f(h.x), e1 = elu_f(h.y);
    float d3[4];
    #pragma unroll
    for (int r = 0; r < 4; ++r)
        d3[r] = elu_f(fmaf(W_dec3[r * 2 + 1], e1, fmaf(W_dec3[r * 2], e0, b_dec3[r])));
    float d2[8];
    #pragma unroll
    for (int r = 0; r < 8; ++r) {
        float a = b_dec2[r];
        #pragma unroll
        for (int j = 0; j < 4; ++j) a = fmaf(W_dec2[r * 4 + j], d3[j], a);
        d2[r] = elu_f(a);
    }
    const float* xl = x + (size_t)l * TDIM * BDIM + b;
    float* ol = out + (size_t)l * TDIM * BDIM + b;
    #pragma unroll
    for (int t = 0; t < TDIM; ++t) {
        float a = b_dec[t] + xl[(size_t)t * BDIM];
        #pragma unroll
        for (int r = 0; r < 8; ++r) a = fmaf(W_dec[t * 8 + r], d2[r], a);
        ol[(size_t)t * BDIM] = elu_f(a);
    }
}

extern "C" void kernel_launch(void* const* d_in, const int* in_sizes, int n_in,
                              void* d_out, int out_size, void* d_ws, size_t ws_size,
                              hipStream_t stream) {
    (void)in_sizes; (void)n_in; (void)out_size; (void)ws_size;
    const float* x_input = (const float*)d_in[0];
    const float* knobs   = (const float*)d_in[1];
    const float* W_enc   = (const float*)d_in[2];
    const float* b_enc   = (const float*)d_in[3];
    const float* W_enc2  = (const float*)d_in[4];
    const float* b_enc2  = (const float*)d_in[5];
    const float* W_enc3  = (const float*)d_in[6];
    const float* b_enc3  = (const float*)d_in[7];
    const float* Wih1    = (const float*)d_in[8];
    const float* Whh1    = (const float*)d_in[9];
    const float* bih1    = (const float*)d_in[10];
    const float* bhh1    = (const float*)d_in[11];
    const float* W_knobs = (const float*)d_in[12];
    const float* b_knobs = (const float*)d_in[13];
    const float* Wih2    = (const float*)d_in[14];
    const float* Whh2    = (const float*)d_in[15];
    const float* bih2    = (const float*)d_in[16];
    const float* bhh2    = (const float*)d_in[17];
    const float* W_dec3  = (const float*)d_in[18];
    const float* b_dec3  = (const float*)d_in[19];
    const float* W_dec2  = (const float*)d_in[20];
    const float* b_dec2  = (const float*)d_in[21];
    const float* W_dec   = (const float*)d_in[22];
    const float* b_dec   = (const float*)d_in[23];

    float* ws = (float*)d_ws;
    float* z_enc = ws;                               // L*B*2 floats
    float* h2buf = z_enc + (size_t)LSEQ * BDIM * 2;  // L*B*2 floats
    float* kn    = h2buf + (size_t)LSEQ * BDIM * 2;  // L*2 floats

    k_enc<<<dim3(LSEQ), dim3(320), 0, stream>>>(
        x_input, knobs, W_enc, b_enc, W_enc2, b_enc2, W_enc3, b_enc3,
        W_knobs, b_knobs, z_enc, kn);
    k_lstm<<<dim3((BDIM + 63) / 64, NCHUNK), dim3(64), 0, stream>>>(
        z_enc, kn, Wih1, Whh1, bih1, bhh1, W_knobs,
        Wih2, Whh2, bih2, bhh2, h2buf);
    k_dec<<<dim3(LSEQ), dim3(320), 0, stream>>>(
        h2buf, x_input, W_dec3, b_dec3, W_dec2, b_dec2, W_dec, b_dec,
        (float*)d_out);
}

// Round 5
// 91.118 us; speedup vs baseline: 1.2220x; 1.2220x over previous
//
#include <hip/hip_runtime.h>
#include <math.h>

#define LSEQ 4096
#define TDIM 25
#define BDIM 257
#define RDIM 8
#define KDIM 3

#define S_CHUNK 8
#define W_WARM 16
#define TOT (S_CHUNK + W_WARM)     // 24 steps per thread
#define NCHUNK (LSEQ / S_CHUNK)    // 512

__device__ __forceinline__ float rcp_f(float x) {
    return __builtin_amdgcn_rcpf(x);    // v_rcp_f32, ~1 ULP
}
__device__ __forceinline__ float elu_f(float x) {
    return x > 0.f ? x : (__expf(x) - 1.f);
}
__device__ __forceinline__ float sig_f(float x) {
    return rcp_f(1.f + __expf(-x));
}
__device__ __forceinline__ float tanh_f(float x) {
    float e = __expf(2.f * x);
    return 1.f - 2.f * rcp_f(e + 1.f);
}

// ---------------- Kernel 1: encoder (parallel over L x B) ----------------
__global__ __launch_bounds__(320) void k_enc(
    const float* __restrict__ x, const float* __restrict__ knobs,
    const float* __restrict__ W_enc, const float* __restrict__ b_enc,
    const float* __restrict__ W_enc2, const float* __restrict__ b_enc2,
    const float* __restrict__ W_enc3, const float* __restrict__ b_enc3,
    const float* __restrict__ Wk, const float* __restrict__ bk,
    float* __restrict__ z_enc, float* __restrict__ kn)
{
    const int l = blockIdx.x;
    const int b = threadIdx.x;
    if (b < BDIM) {
        const float* xl = x + (size_t)l * TDIM * BDIM + b;
        float xr[TDIM];
        #pragma unroll
        for (int t = 0; t < TDIM; ++t) xr[t] = xl[(size_t)t * BDIM];
        float z1[RDIM];
        #pragma unroll
        for (int r = 0; r < RDIM; ++r) {
            float a = b_enc[r];
            #pragma unroll
            for (int t = 0; t < TDIM; ++t) a = fmaf(W_enc[r * TDIM + t], xr[t], a);
            z1[r] = elu_f(a);
        }
        float z2[RDIM / 2];
        #pragma unroll
        for (int r = 0; r < RDIM / 2; ++r) {
            float a = b_enc2[r];
            #pragma unroll
            for (int j = 0; j < RDIM; ++j) a = fmaf(W_enc2[r * RDIM + j], z1[j], a);
            z2[r] = elu_f(a);
        }
        float z30 = b_enc3[0], z31 = b_enc3[1];
        #pragma unroll
        for (int j = 0; j < RDIM / 2; ++j) {
            z30 = fmaf(W_enc3[j], z2[j], z30);
            z31 = fmaf(W_enc3[RDIM / 2 + j], z2[j], z31);
        }
        reinterpret_cast<float2*>(z_enc)[(size_t)l * BDIM + b] =
            make_float2(elu_f(z30), elu_f(z31));
    } else if (b == BDIM) {
        float k0 = knobs[l * KDIM + 0], k1 = knobs[l * KDIM + 1], k2 = knobs[l * KDIM + 2];
        float2 kv;
        kv.x = bk[0] + Wk[0 * 5 + 2] * k0 + Wk[0 * 5 + 3] * k1 + Wk[0 * 5 + 4] * k2;
        kv.y = bk[1] + Wk[1 * 5 + 2] * k0 + Wk[1 * 5 + 3] * k1 + Wk[1 * 5 + 4] * k2;
        reinterpret_cast<float2*>(kn)[l] = kv;
    }
}

// ---------------- Kernel 2: fused LSTM1 -> mid -> LSTM2 -> decoder ----------------
struct LState {
    float h1x, h1y, c1x, c1y, h2x, h2y, c2x, c2y;
};

template <typename WT>
__device__ __forceinline__ void lstm_step(
    LState& s, float2 xe, float2 kv, const WT& w)
{
    // ---- LSTM1 ---- gate order i,f,g,o (4H=8, H=2)
    float g[8];
    #pragma unroll
    for (int j = 0; j < 8; ++j)
        g[j] = fmaf(w.wh1[j][1], s.h1y, fmaf(w.wh1[j][0], s.h1x,
               fmaf(w.wi1[j][1], xe.y, fmaf(w.wi1[j][0], xe.x, w.bb1[j]))));
    s.c1x = fmaf(sig_f(g[2]), s.c1x, sig_f(g[0]) * tanh_f(g[4]));
    s.c1y = fmaf(sig_f(g[3]), s.c1y, sig_f(g[1]) * tanh_f(g[5]));
    s.h1x = sig_f(g[6]) * tanh_f(s.c1x);
    s.h1y = sig_f(g[7]) * tanh_f(s.c1y);
    // ---- mid (knobs) layer ----
    float e0 = elu_f(s.h1x), e1 = elu_f(s.h1y);
    float m0 = elu_f(fmaf(w.wk01, e1, fmaf(w.wk00, e0, kv.x)));
    float m1 = elu_f(fmaf(w.wk11, e1, fmaf(w.wk10, e0, kv.y)));
    // ---- LSTM2 ----
    float g2[8];
    #pragma unroll
    for (int j = 0; j < 8; ++j)
        g2[j] = fmaf(w.wh2[j][1], s.h2y, fmaf(w.wh2[j][0], s.h2x,
                fmaf(w.wi2[j][1], m1, fmaf(w.wi2[j][0], m0, w.bb2[j]))));
    s.c2x = fmaf(sig_f(g2[2]), s.c2x, sig_f(g2[0]) * tanh_f(g2[4]));
    s.c2y = fmaf(sig_f(g2[3]), s.c2y, sig_f(g2[1]) * tanh_f(g2[5]));
    s.h2x = sig_f(g2[6]) * tanh_f(s.c2x);
    s.h2y = sig_f(g2[7]) * tanh_f(s.c2y);
}

struct LWeights {
    float wi1[8][2], wh1[8][2], bb1[8];
    float wi2[8][2], wh2[8][2], bb2[8];
    float wk00, wk01, wk10, wk11;
};

__global__ __launch_bounds__(64) void k_lstm_dec(
    const float* __restrict__ z_enc, const float* __restrict__ kn,
    const float* __restrict__ Wih1, const float* __restrict__ Whh1,
    const float* __restrict__ bih1, const float* __restrict__ bhh1,
    const float* __restrict__ Wk,
    const float* __restrict__ Wih2, const float* __restrict__ Whh2,
    const float* __restrict__ bih2, const float* __restrict__ bhh2,
    const float* __restrict__ W_dec3, const float* __restrict__ b_dec3,
    const float* __restrict__ W_dec2, const float* __restrict__ b_dec2,
    const float* __restrict__ W_dec, const float* __restrict__ b_dec,
    const float* __restrict__ x, float* __restrict__ out)
{
    __shared__ float2 zs[TOT][64];

    const int tid = threadIdx.x;
    const int b = blockIdx.x * 64 + tid;
    const int bb = b < BDIM ? b : BDIM - 1;     // clamp for safe reads
    const bool active = b < BDIM;
    const int chunk = blockIdx.y;
    const int l0 = chunk * S_CHUNK;
    const int ls = l0 - W_WARM;                 // may be negative (chunks 0..1)

    const float2* ze = reinterpret_cast<const float2*>(z_enc);
    const float2* knv = reinterpret_cast<const float2*>(kn);

    // ---- stage z window: TOT independent coalesced loads, one latency ----
    #pragma unroll
    for (int i = 0; i < TOT; ++i) {
        int l = ls + i; int lc = l < 0 ? 0 : l;
        zs[i][tid] = ze[(size_t)lc * BDIM + bb];
    }
    __syncthreads();

    // ---- weights (lane-invariant -> scalar regs) ----
    LWeights w;
    #pragma unroll
    for (int j = 0; j < 8; ++j) {
        w.wi1[j][0] = Wih1[j * 2]; w.wi1[j][1] = Wih1[j * 2 + 1];
        w.wh1[j][0] = Whh1[j * 2]; w.wh1[j][1] = Whh1[j * 2 + 1];
        w.bb1[j] = bih1[j] + bhh1[j];
        w.wi2[j][0] = Wih2[j * 2]; w.wi2[j][1] = Wih2[j * 2 + 1];
        w.wh2[j][0] = Whh2[j * 2]; w.wh2[j][1] = Whh2[j * 2 + 1];
        w.bb2[j] = bih2[j] + bhh2[j];
    }
    w.wk00 = Wk[0]; w.wk01 = Wk[1]; w.wk10 = Wk[5]; w.wk11 = Wk[6];

    LState s = {0.f, 0.f, 0.f, 0.f, 0.f, 0.f, 0.f, 0.f};

    // ---- warmup (no output) ----
    #pragma unroll 4
    for (int i = 0; i < W_WARM; ++i) {
        const int l = ls + i;
        if (l < 0) continue;                    // wave-uniform: state stays zero
        lstm_step(s, zs[i][tid], knv[l], w);
    }
    // ---- body: keep h2 in registers (static slots) ----
    float2 h2s[S_CHUNK];
    #pragma unroll
    for (int i = 0; i < S_CHUNK; ++i) {
        lstm_step(s, zs[W_WARM + i][tid], knv[l0 + i], w);
        h2s[i] = make_float2(s.h2x, s.h2y);
    }

    // ---- decoder phase: d2 for all 8 rows (static indexing) ----
    float d2a[S_CHUNK][8];
    #pragma unroll
    for (int i = 0; i < S_CHUNK; ++i) {
        float e0 = elu_f(h2s[i].x), e1 = elu_f(h2s[i].y);
        float d3[4];
        #pragma unroll
        for (int r = 0; r < 4; ++r)
            d3[r] = elu_f(fmaf(W_dec3[r * 2 + 1], e1, fmaf(W_dec3[r * 2], e0, b_dec3[r])));
        #pragma unroll
        for (int r = 0; r < 8; ++r) {
            float a = b_dec2[r];
            #pragma unroll
            for (int j = 0; j < 4; ++j) a = fmaf(W_dec2[r * 4 + j], d3[j], a);
            d2a[i][r] = elu_f(a);
        }
    }

    // ---- output: t outer so W_dec row (s_load) amortizes over 8 l's ----
    const float* xb = x + bb;
    float* ob = out + b;
    #pragma unroll 5
    for (int t = 0; t < TDIM; ++t) {
        float wr[8];
        #pragma unroll
        for (int r = 0; r < 8; ++r) wr[r] = W_dec[t * 8 + r];
        const float bt = b_dec[t];
        float res[S_CHUNK];
        #pragma unroll
        for (int i = 0; i < S_CHUNK; ++i) {
            const size_t idx = ((size_t)(l0 + i) * TDIM + t) * BDIM;
            float a = bt + xb[idx];
            #pragma unroll
            for (int r = 0; r < 8; ++r) a = fmaf(wr[r], d2a[i][r], a);
            res[i] = elu_f(a);
        }
        if (active) {
            #pragma unroll
            for (int i = 0; i < S_CHUNK; ++i) {
                const size_t idx = ((size_t)(l0 + i) * TDIM + t) * BDIM;
                ob[idx] = res[i];
            }
        }
    }
}

extern "C" void kernel_launch(void* const* d_in, const int* in_sizes, int n_in,
                              void* d_out, int out_size, void* d_ws, size_t ws_size,
                              hipStream_t stream) {
    (void)in_sizes; (void)n_in; (void)out_size; (void)ws_size;
    const float* x_input = (const float*)d_in[0];
    const float* knobs   = (const float*)d_in[1];
    const float* W_enc   = (const float*)d_in[2];
    const float* b_enc   = (const float*)d_in[3];
    const float* W_enc2  = (const float*)d_in[4];
    const float* b_enc2  = (const float*)d_in[5];
    const float* W_enc3  = (const float*)d_in[6];
    const float* b_enc3  = (const float*)d_in[7];
    const float* Wih1    = (const float*)d_in[8];
    const float* Whh1    = (const float*)d_in[9];
    const float* bih1    = (const float*)d_in[10];
    const float* bhh1    = (const float*)d_in[11];
    const float* W_knobs = (const float*)d_in[12];
    const float* b_knobs = (const float*)d_in[13];
    const float* Wih2    = (const float*)d_in[14];
    const float* Whh2    = (const float*)d_in[15];
    const float* bih2    = (const float*)d_in[16];
    const float* bhh2    = (const float*)d_in[17];
    const float* W_dec3  = (const float*)d_in[18];
    const float* b_dec3  = (const float*)d_in[19];
    const float* W_dec2  = (const float*)d_in[20];
    const float* b_dec2  = (const float*)d_in[21];
    const float* W_dec   = (const float*)d_in[22];
    const float* b_dec   = (const float*)d_in[23];

    float* ws = (float*)d_ws;
    float* z_enc = ws;                               // L*B*2 floats
    float* kn    = z_enc + (size_t)LSEQ * BDIM * 2;  // L*2 floats

    k_enc<<<dim3(LSEQ), dim3(320), 0, stream>>>(
        x_input, knobs, W_enc, b_enc, W_enc2, b_enc2, W_enc3, b_enc3,
        W_knobs, b_knobs, z_enc, kn);
    k_lstm_dec<<<dim3((BDIM + 63) / 64, NCHUNK), dim3(64), 0, stream>>>(
        z_enc, kn, Wih1, Whh1, bih1, bhh1, W_knobs,
        Wih2, Whh2, bih2, bhh2,
        W_dec3, b_dec3, W_dec2, b_dec2, W_dec, b_dec,
        x_input, (float*)d_out);
}